// Round 10
// baseline (846.778 us; speedup 1.0000x reference)
//
#include <hip/hip_runtime.h>
#include <math.h>

// ---------------- problem constants ----------------
constexpr int B    = 256;
constexpr int M    = 256;
constexpr int A    = 33;
constexpr int NH   = 3;
constexpr int NO   = 100;     // NOUT
constexpr int FIN  = 66;      // 2*S+2
constexpr int OBSD = 17666;   // 5*M+2 + 2*M*S
constexpr int D1   = 770;     // 3*M+2
constexpr int D2G  = 76800;   // M * NH * NO (gat part of concat)

__device__ __forceinline__ float lrelu(float x) { return x > 0.f ? x : 0.01f * x; }
__device__ __forceinline__ float eluf(float x)  { return x > 0.f ? x : expm1f(x); }

// ---------------- K0: adjacency bitmask ----------------
__global__ __launch_bounds__(256) void k_adjmask(const int* __restrict__ adj,
                                                 unsigned* __restrict__ adjm) {
  int w = blockIdx.x * 256 + threadIdx.x;       // 2048 words: [i][8]
  if (w >= M * 8) return;
  int i = w >> 3, wd = w & 7;
  const int* row = adj + i * M + wd * 32;
  unsigned mval = 0;
  #pragma unroll
  for (int bit = 0; bit < 32; ++bit) mval |= (row[bit] > 0 ? 1u : 0u) << bit;
  adjm[w] = mval;
}

// ---------------- K1: Wh = feat @ W_gat  (+ fused e1/e2 + fused colstats) -------
__global__ __launch_bounds__(256) void k_wh(const float* __restrict__ obs,
                                            const float* __restrict__ Wg,
                                            const float* __restrict__ ag,
                                            const unsigned* __restrict__ adjm,
                                            float* __restrict__ Wh,
                                            float* __restrict__ e1,
                                            float* __restrict__ e2,
                                            float* __restrict__ cmax,
                                            float* __restrict__ csum) {
  int b = blockIdx.x, h = blockIdx.y;
  int t = threadIdx.x;
  int to = t >> 4;          // 0..15 -> o = to*8 .. +7 (o<100 valid)
  int tm = t & 15;          // m-quads: {tm*4..+3, 64+tm*4..+3}
  __shared__ float smem_w[66 * 104 + 32];   // W[f][o], rows padded to 104
  __shared__ float featT[66 * 132];         // featT[f][m], rows padded to 132
  __shared__ float a1s[128], a2s[128];
  __shared__ float e1a[256], e2a[256];
  __shared__ unsigned ams[M * 8];           // adjacency bitmask [i][8]
  const float* ob = obs + (size_t)b * OBSD;

  for (int idx = t; idx < 66 * 104 + 32; idx += 256) {
    float v = 0.f;
    if (idx < 66 * 104) {
      int f = idx / 104, o = idx % 104;
      if (o < NO) v = Wg[((size_t)h * FIN + f) * NO + o];
    }
    smem_w[idx] = v;
  }
  if (t < 128) {
    a1s[t] = (t < NO) ? ag[h * 200 + t] : 0.f;
    a2s[t] = (t < NO) ? ag[h * 200 + NO + t] : 0.f;
  }
  for (int w = t; w < M * 8; w += 256) ams[w] = adjm[w];

  size_t basee = ((size_t)h * B + b) * M;

  for (int tile = 0; tile < 2; ++tile) {
    int m0 = tile * 128;
    if (t < 128)       featT[t]               = ob[770  + m0 + t];
    else               featT[132 + (t - 128)] = ob[1026 + m0 + (t - 128)];
    for (int idx = t; idx < 128 * 32; idx += 256) {
      int m = idx >> 5, s = idx & 31;
      featT[(2  + s) * 132 + m] = ob[1282 + (size_t)(m0 + m) * 32 + s];
      featT[(34 + s) * 132 + m] = ob[9474 + (size_t)(m0 + m) * 32 + s];
    }
    __syncthreads();

    float acc[8][8];
    #pragma unroll
    for (int q = 0; q < 8; ++q)
      #pragma unroll
      for (int p = 0; p < 8; ++p) acc[q][p] = 0.f;

    const float* frP = featT;
    const float* wrP = smem_w + to * 8;
    for (int f = 0; f < 66; ++f) {
      float4 fa = *(const float4*)(frP + tm * 4);        // m = tm*4..+3
      float4 fb = *(const float4*)(frP + 64 + tm * 4);   // m = 64+tm*4..+3
      float4 wa = *(const float4*)wrP;
      float4 wb = *(const float4*)(wrP + 4);
      float fm[8] = {fa.x, fa.y, fa.z, fa.w, fb.x, fb.y, fb.z, fb.w};
      float wv[8] = {wa.x, wa.y, wa.z, wa.w, wb.x, wb.y, wb.z, wb.w};
      #pragma unroll
      for (int q = 0; q < 8; ++q)
        #pragma unroll
        for (int p = 0; p < 8; ++p) acc[q][p] = fmaf(fm[q], wv[p], acc[q][p]);
      frP += 132;
      wrP += 104;
    }
    __syncthreads();

    float* e1p = featT;              // [128][18] partials (alias featT)
    float* e2p = featT + 128 * 18;
    #pragma unroll
    for (int q = 0; q < 8; ++q) {
      int ml = (q < 4) ? (tm * 4 + q) : (64 + tm * 4 + q - 4);
      float p1 = 0.f, p2 = 0.f;
      #pragma unroll
      for (int p = 0; p < 8; ++p) {
        float av = acc[q][p];
        p1 += av * a1s[to * 8 + p];
        p2 += av * a2s[to * 8 + p];
      }
      e1p[ml * 18 + to] = p1;
      e2p[ml * 18 + to] = p2;
    }

    #pragma unroll
    for (int q = 0; q < 8; ++q) {
      int ml = (q < 4) ? (tm * 4 + q) : (64 + tm * 4 + q - 4);
      int m = m0 + ml;
      float* wp = Wh + (basee + m) * NO + to * 8;
      if (to <= 12) *(float4*)wp       = make_float4(acc[q][0], acc[q][1], acc[q][2], acc[q][3]);
      if (to <= 11) *(float4*)(wp + 4) = make_float4(acc[q][4], acc[q][5], acc[q][6], acc[q][7]);
    }
    __syncthreads();

    if (t < 128) {
      float s1 = 0.f, s2 = 0.f;
      #pragma unroll
      for (int u = 0; u < 16; ++u) {
        s1 += e1p[t * 18 + u];
        s2 += e2p[t * 18 + u];
      }
      e1[basee + m0 + t] = s1;
      e2[basee + m0 + t] = s2;
      e1a[m0 + t] = s1;
      e2a[m0 + t] = s2;
    }
    __syncthreads();
  }

  // ---- fused colstats: softmax-over-i stats for column j = t ----
  {
    float e2j = e2a[t];
    int jw = t >> 5;
    unsigned jb = 1u << (t & 31);
    float mx = -INFINITY;
    #pragma unroll 8
    for (int i = 0; i < M; ++i) {
      float v = (ams[i * 8 + jw] & jb) ? lrelu(e1a[i] + e2j) : -9e15f;
      mx = fmaxf(mx, v);
    }
    float sm = 0.f;
    #pragma unroll 8
    for (int i = 0; i < M; ++i) {
      float v = (ams[i * 8 + jw] & jb) ? lrelu(e1a[i] + e2j) : -9e15f;
      sm += expf(v - mx);
    }
    cmax[basee + t] = mx;
    csum[basee + t] = sm;
  }
}

// ---------------- K4: h_prime = att @ Wh (tiled GEMM), elu -> feats ----------------
// One launch per h (grid B x 2) so every kernel's duration becomes visible in
// top-5 profiling. WhC chunk prefetched to registers (issue c+1 loads before
// GEMM of c -> L3 latency hidden under compute). fmaf + pointer-bump inner loop.
__global__ __launch_bounds__(256) void k_attn(const float* __restrict__ Wh,
                                              const float* __restrict__ e1,
                                              const float* __restrict__ e2,
                                              const float* __restrict__ cmax,
                                              const float* __restrict__ csum,
                                              const unsigned* __restrict__ adjm,
                                              float* __restrict__ feats,
                                              int h) {
  int b = blockIdx.x, ih = blockIdx.y;
  int t = threadIdx.x;
  int to = t & 15, ti = t >> 4;
  int i0 = ih * 128;
  __shared__ float WhC[32 * 128];        // 16 KB (cols >=100 zero)
  __shared__ float attT[32 * 132];       // 16.9 KB
  __shared__ float e1s[128];
  __shared__ float e2s[256], cms[256], csr[256];
  size_t base = ((size_t)h * B + b) * M;

  if (t < 128) e1s[t] = e1[base + i0 + t];
  e2s[t] = e2[base + t];
  cms[t] = cmax[base + t];
  csr[t] = 1.0f / csum[base + t];

  float acc[8][8];
  #pragma unroll
  for (int q = 0; q < 8; ++q)
    #pragma unroll
    for (int p = 0; p < 8; ++p) acc[q][p] = 0.f;

  const float* WhG = Wh + base * NO;
  int jp = t >> 3;            // staging: j' 0..31
  int ib = t & 7;             // staging: i = ib + 8*rr (strided)
  // prefetch mapping: 4 float4 per thread; idx4 = t + 256u -> r=idx4>>5, o4=idx4&31
  int pr_r[4], pr_o4[4];
  #pragma unroll
  for (int u = 0; u < 4; ++u) {
    int idx4 = t + 256 * u;
    pr_r[u]  = idx4 >> 5;
    pr_o4[u] = idx4 & 31;
  }
  float4 pf[4];
  #pragma unroll
  for (int u = 0; u < 4; ++u)
    pf[u] = (pr_o4[u] < 25)
          ? *(const float4*)(WhG + (size_t)pr_r[u] * NO + pr_o4[u] * 4)
          : make_float4(0.f, 0.f, 0.f, 0.f);

  for (int c = 0; c < 8; ++c) {
    __syncthreads();          // previous chunk fully consumed (and init writes done)
    // write prefetched WhC chunk regs -> LDS
    #pragma unroll
    for (int u = 0; u < 4; ++u)
      *(float4*)(WhC + pr_r[u] * 128 + pr_o4[u] * 4) = pf[u];
    // stage attT[j][i] (strided-i, bank-clean)
    {
      int jg = c * 32 + jp;
      float e2j = e2s[jg], cmj = cms[jg], rsj = csr[jg];
      unsigned wbit = 1u << jp;                       // jg & 31 == jp
      const unsigned* aw = adjm + (size_t)(i0 + ib) * 8 + c;   // jg>>5 == c
      const float* ep = e1s + ib;
      float* ap = attT + jp * 132 + ib;
      #pragma unroll
      for (int rr = 0; rr < 16; ++rr) {
        float v = (aw[rr * 64] & wbit) ? lrelu(ep[rr * 8] + e2j) : -9e15f;
        ap[rr * 8] = expf(v - cmj) * rsj;
      }
    }
    // issue prefetch for chunk c+1 (consumed after next barrier -> latency hidden)
    if (c < 7) {
      const float* WhN = WhG + (size_t)(c + 1) * 32 * NO;
      #pragma unroll
      for (int u = 0; u < 4; ++u)
        pf[u] = (pr_o4[u] < 25)
              ? *(const float4*)(WhN + (size_t)pr_r[u] * NO + pr_o4[u] * 4)
              : make_float4(0.f, 0.f, 0.f, 0.f);
    }
    __syncthreads();
    // GEMM: 32 j-steps, 8x8 per thread (split-o), fmaf + pointer bump
    const float* aP  = attT + ti * 8;
    const float* wP0 = WhC + to * 4;
    const float* wP1 = WhC + 64 + to * 4;
    for (int j = 0; j < 32; ++j) {
      float4 aa = *(const float4*)aP;
      float4 ab = *(const float4*)(aP + 4);
      float4 wa = *(const float4*)wP0;
      float4 wb = *(const float4*)wP1;
      float av[8] = {aa.x, aa.y, aa.z, aa.w, ab.x, ab.y, ab.z, ab.w};
      float wv[8] = {wa.x, wa.y, wa.z, wa.w, wb.x, wb.y, wb.z, wb.w};
      #pragma unroll
      for (int q = 0; q < 8; ++q)
        #pragma unroll
        for (int p = 0; p < 8; ++p) acc[q][p] = fmaf(av[q], wv[p], acc[q][p]);
      aP  += 132;
      wP0 += 128;
      wP1 += 128;
    }
  }

  // epilogue: elu + direct stores; o = to*4 (always valid), 64+to*4 (to<9)
  #pragma unroll
  for (int q = 0; q < 8; ++q) {
    int i = i0 + ti * 8 + q;
    float* fp = feats + ((size_t)b * M + i) * 300 + h * NO;
    *(float4*)(fp + to * 4) =
        make_float4(eluf(acc[q][0]), eluf(acc[q][1]), eluf(acc[q][2]), eluf(acc[q][3]));
    if (to < 9)
      *(float4*)(fp + 64 + to * 4) =
          make_float4(eluf(acc[q][4]), eluf(acc[q][5]), eluf(acc[q][6]), eluf(acc[q][7]));
  }
}

// ---------------- K7: split-K GEMM, fused LN stats + LN + elu on staging --------
// Block (bt,dc) covers rows m = dc*4..+3 FULLY (1200 = 4x300 aligned), so the
// LayerNorm stats for its 64 (b,m) rows are computed in-block (deterministic
// fixed-order sums) -> k_lnstats kernel and its 78.6 MB re-read eliminated.
__global__ __launch_bounds__(256) void k_gemm2(const float* __restrict__ gat,
                                               const float* __restrict__ lw,
                                               const float* __restrict__ lb,
                                               const float* __restrict__ W2,
                                               float* __restrict__ pre) {
  int bt = blockIdx.x, dc = blockIdx.y;
  int t = threadIdx.x;
  int k = t & 127, g2 = t >> 7;
  __shared__ float gt[16 * 124];
  __shared__ float mu_s[64], rs_s[64];
  __shared__ float part[64][4];
  int b0 = bt * 16, d0 = dc * 1200;

  // ---- LN stats for the block's 64 rows (16 b x 4 m) ----
  {
    int row = t >> 2, seg = t & 3;         // row = blocal*4 + mlocal
    int brow = b0 + (row >> 2);
    int mloc = row & 3;
    const float* rp = gat + (size_t)brow * D2G + (size_t)(dc * 4 + mloc) * 300 + seg * 75;
    float s = 0.f;
    #pragma unroll 5
    for (int i = 0; i < 75; ++i) s += rp[i];
    part[row][seg] = s;
    __syncthreads();
    if (t < 64)
      mu_s[t] = (part[t][0] + part[t][1] + part[t][2] + part[t][3]) * (1.f / 300.f);
    __syncthreads();
    float mu = mu_s[row];
    float ss = 0.f;
    #pragma unroll 5
    for (int i = 0; i < 75; ++i) { float d = rp[i] - mu; ss += d * d; }
    part[row][seg] = ss;
    __syncthreads();
    if (t < 64)
      rs_s[t] = 1.0f / sqrtf((part[t][0] + part[t][1] + part[t][2] + part[t][3]) * (1.f / 300.f) + 1e-5f);
    __syncthreads();
  }

  float acc[8];
  #pragma unroll
  for (int r = 0; r < 8; ++r) acc[r] = 0.f;
  for (int ds0 = 0; ds0 < 1200; ds0 += 120) {
    int dsg = d0 + ds0;
    __syncthreads();
    for (int idx = t; idx < 16 * 120; idx += 256) {
      int rr = idx / 120, cc = idx - rr * 120;
      int gidx = dsg + cc;
      int brow = b0 + rr;
      int mrow = gidx / 300;
      int d    = gidx - mrow * 300;
      int lr   = rr * 4 + (mrow - dc * 4);
      float x = gat[(size_t)brow * D2G + gidx];
      float val = (x - mu_s[lr]) * rs_s[lr] * lw[d] + lb[d];
      gt[rr * 124 + cc] = eluf(val);
    }
    __syncthreads();
    const float* w2p = W2 + (size_t)(100 + dsg) * 128 + k;
    for (int c4 = 0; c4 < 30; ++c4) {
      float w0  = w2p[(size_t)(c4 * 4 + 0) * 128];
      float w1  = w2p[(size_t)(c4 * 4 + 1) * 128];
      float w2v = w2p[(size_t)(c4 * 4 + 2) * 128];
      float w3  = w2p[(size_t)(c4 * 4 + 3) * 128];
      #pragma unroll
      for (int r = 0; r < 8; ++r) {
        float4 gv = *(const float4*)(gt + (g2 * 8 + r) * 124 + c4 * 4);
        acc[r] = fmaf(gv.x, w0, acc[r]);
        acc[r] = fmaf(gv.y, w1, acc[r]);
        acc[r] = fmaf(gv.z, w2v, acc[r]);
        acc[r] = fmaf(gv.w, w3, acc[r]);
      }
    }
  }
  #pragma unroll
  for (int r = 0; r < 8; ++r)
    pre[((size_t)dc * B + b0 + g2 * 8 + r) * 128 + k] = acc[r];
}

// ---------------- K8: hidden = relu(elu(sf-part + dc-partials + b2)), sf fused ---
__global__ __launch_bounds__(256) void k_hid(const float* __restrict__ pre,
                                             const float* __restrict__ obs,
                                             const float* __restrict__ W1,
                                             const float* __restrict__ b1,
                                             const float* __restrict__ W2,
                                             const float* __restrict__ b2,
                                             float* __restrict__ hid,
                                             float* __restrict__ hidT) {
  int b = blockIdx.x, t = threadIdx.x;
  int k = t & 127, p = t >> 7;
  __shared__ float ssrv[D1];
  __shared__ float sfs[128];
  __shared__ float red[256];
  const float* ob = obs + (size_t)b * OBSD;
  for (int i = t; i < D1; i += 256) ssrv[i] = ob[i];
  __syncthreads();
  // ---- server_feat (old k_sf, identical arithmetic/order) ----
  float acc = 0.f;
  if (k < NO) {
    int f0 = p * 385;
    #pragma unroll 8
    for (int f = f0; f < f0 + 385; ++f) acc += ssrv[f] * W1[(size_t)f * NO + k];
  }
  red[t] = acc;
  __syncthreads();
  if (t < 128 && k < NO) {
    float v = red[t] + red[t + 128] + b1[k];
    sfs[k] = fmaxf(eluf(v), 0.f);
  }
  __syncthreads();
  // ---- hidden ----
  float s = 0.f;
  #pragma unroll 4
  for (int dc = p * 32; dc < p * 32 + 32; ++dc)
    s += pre[((size_t)dc * B + b) * 128 + k];
  #pragma unroll 4
  for (int f = p * 50; f < p * 50 + 50; ++f)
    s += sfs[f] * W2[(size_t)f * 128 + k];
  __syncthreads();
  red[t] = s;
  __syncthreads();
  if (t < 128) {
    float v = red[t] + red[t + 128] + b2[k];
    v = fmaxf(eluf(v), 0.f);
    hid[(size_t)b * 128 + k] = v;
    hidT[(size_t)k * B + b]  = v;
  }
}

// ---------------- K9: logits -> gumbel one-hot output ----------------
__global__ __launch_bounds__(256) void k_out(const float* __restrict__ hidT,
                                             const float* __restrict__ Wout,
                                             const float* __restrict__ bout,
                                             const float* __restrict__ ug,
                                             float* __restrict__ out) {
  int m = blockIdx.x, b = threadIdx.x;
  __shared__ float wo[128 * 36];
  for (int idx = b; idx < 128 * 36; idx += 256) {
    int kk = idx / 36, a = idx % 36;
    wo[idx] = (a < A) ? Wout[(size_t)m * 128 * A + kk * A + a] : 0.f;
  }
  __syncthreads();
  float l[36];
  #pragma unroll
  for (int a = 0; a < 36; ++a) l[a] = (a < A) ? bout[m * A + a] : 0.f;
  for (int kk = 0; kk < 128; ++kk) {
    float hv = hidT[(size_t)kk * B + b];
    const float4* w4 = (const float4*)(wo + kk * 36);
    #pragma unroll
    for (int q = 0; q < 9; ++q) {
      float4 wv = w4[q];
      l[4*q+0] = fmaf(hv, wv.x, l[4*q+0]);
      l[4*q+1] = fmaf(hv, wv.y, l[4*q+1]);
      l[4*q+2] = fmaf(hv, wv.z, l[4*q+2]);
      l[4*q+3] = fmaf(hv, wv.w, l[4*q+3]);
    }
  }
  const float* ugp = ug + ((size_t)b * M + m) * A;
  float mx = -INFINITY;
  int amx = 0;
  #pragma unroll
  for (int a = 0; a < A; ++a) {
    float th = tanhf(eluf(l[a]));
    float u = ugp[a];
    u = fminf(fmaxf(u, 1e-10f), 1.0f - 1e-10f);
    float gb = -logf(-logf(u));
    float z = th + gb;
    l[a] = z;
    if (z > mx) { mx = z; amx = a; }
  }
  float sm = 0.f;
  #pragma unroll
  for (int a = 0; a < A; ++a) { float e = expf(l[a] - mx); l[a] = e; sm += e; }
  float* op = out + ((size_t)b * M + m) * A;
  #pragma unroll
  for (int a = 0; a < A; ++a) {
    float ys = l[a] / sm;
    float yh = (a == amx) ? 1.0f : 0.0f;
    op[a] = (yh + ys) - ys;
  }
}

// ---------------- launcher ----------------
extern "C" void kernel_launch(void* const* d_in, const int* in_sizes, int n_in,
                              void* d_out, int out_size, void* d_ws, size_t ws_size,
                              hipStream_t stream) {
  const float* obs  = (const float*)d_in[0];
  const int*   adj  = (const int*)  d_in[1];
  const float* ug   = (const float*)d_in[2];
  const float* Wg   = (const float*)d_in[3];
  const float* ag   = (const float*)d_in[4];
  const float* lw   = (const float*)d_in[5];
  const float* lb   = (const float*)d_in[6];
  const float* W1   = (const float*)d_in[7];
  const float* b1   = (const float*)d_in[8];
  const float* W2   = (const float*)d_in[9];
  const float* b2   = (const float*)d_in[10];
  const float* Wout = (const float*)d_in[11];
  const float* bout = (const float*)d_in[12];
  float* out = (float*)d_out;

  float* ws = (float*)d_ws;
  size_t off = 0;
  float* Wh    = ws + off; off += (size_t)NH * B * M * NO;   // 19,660,800
  float* feats = ws + off; off += (size_t)B * M * 300;       // 19,660,800
  float* e1    = ws + off; off += (size_t)NH * B * M;
  float* e2    = ws + off; off += (size_t)NH * B * M;
  float* cmx   = ws + off; off += (size_t)NH * B * M;
  float* csm   = ws + off; off += (size_t)NH * B * M;
  float* pre   = ws + off; off += (size_t)64 * B * 128;
  float* hid   = ws + off; off += (size_t)B * 128;
  float* hidT  = ws + off; off += (size_t)B * 128;
  unsigned* adjm = (unsigned*)(ws + off);

  k_adjmask <<<dim3(8),       256, 0, stream>>>(adj, adjm);
  k_wh      <<<dim3(B, NH),   256, 0, stream>>>(obs, Wg, ag, adjm, Wh, e1, e2, cmx, csm);
  k_attn    <<<dim3(B, 2),    256, 0, stream>>>(Wh, e1, e2, cmx, csm, adjm, feats, 0);
  k_attn    <<<dim3(B, 2),    256, 0, stream>>>(Wh, e1, e2, cmx, csm, adjm, feats, 1);
  k_attn    <<<dim3(B, 2),    256, 0, stream>>>(Wh, e1, e2, cmx, csm, adjm, feats, 2);
  k_gemm2   <<<dim3(16, 64),  256, 0, stream>>>(feats, lw, lb, W2, pre);
  k_hid     <<<dim3(B),       256, 0, stream>>>(pre, obs, W1, b1, W2, b2, hid, hidT);
  k_out     <<<dim3(M),       256, 0, stream>>>(hidT, Wout, bout, ug, out);
}